// Round 1
// baseline (55.410 us; speedup 1.0000x reference)
//
#include <hip/hip_runtime.h>

// out[b, w] = prod_{q<=w} cos(x[b,q]) * cos(params[q])
//
// Derivation: initial |0..0> is a product state; RX/RY keep it a product
// state with per-qubit <Z> = cos(p_q)*cos(x_q). The CNOT chain permutes
// basis states so final bit w = XOR of pre-CNOT bits 0..w; independence of
// product-state bits gives <Z_w> = prod of per-qubit <Z> over q<=w.

#define N_WIRES 10

__global__ __launch_bounds__(64) void qcircuit_expval(
    const float* __restrict__ x, const float* __restrict__ p,
    float* __restrict__ out, int batch)
{
    __shared__ float cp[N_WIRES];
    if (threadIdx.x < N_WIRES) cp[threadIdx.x] = __cosf(p[threadIdx.x]);
    __syncthreads();

    int b = blockIdx.x * blockDim.x + threadIdx.x;
    if (b >= batch) return;

    // Row of 10 floats = 40 bytes, 8-byte aligned -> 5x float2 vector loads.
    const float2* xr = reinterpret_cast<const float2*>(x + (size_t)b * N_WIRES);
    float2 xv[N_WIRES / 2];
#pragma unroll
    for (int i = 0; i < N_WIRES / 2; ++i) xv[i] = xr[i];

    float r = 1.0f;
    float2 o[N_WIRES / 2];
#pragma unroll
    for (int i = 0; i < N_WIRES / 2; ++i) {
        r *= cp[2 * i]     * __cosf(xv[i].x);
        o[i].x = r;
        r *= cp[2 * i + 1] * __cosf(xv[i].y);
        o[i].y = r;
    }

    float2* orow = reinterpret_cast<float2*>(out + (size_t)b * N_WIRES);
#pragma unroll
    for (int i = 0; i < N_WIRES / 2; ++i) orow[i] = o[i];
}

extern "C" void kernel_launch(void* const* d_in, const int* in_sizes, int n_in,
                              void* d_out, int out_size, void* d_ws, size_t ws_size,
                              hipStream_t stream) {
    const float* x = (const float*)d_in[0];   // (B, 10) float32
    const float* p = (const float*)d_in[1];   // (10,)  float32
    float* out = (float*)d_out;               // (B, 10) float32

    int batch = in_sizes[0] / N_WIRES;
    const int block = 64;
    int grid = (batch + block - 1) / block;
    qcircuit_expval<<<grid, block, 0, stream>>>(x, p, out, batch);
}

// Round 2
// 54.953 us; speedup vs baseline: 1.0083x; 1.0083x over previous
//
#include <hip/hip_runtime.h>

// out[b, w] = prod_{q<=w} cos(x[b,q]) * cos(params[q])
//
// Derivation: initial |0..0> is a product state; RX/RY keep it a product
// state with per-qubit <Z> = cos(p_q)*cos(x_q). The CNOT chain permutes
// basis states so final bit w = XOR of pre-CNOT bits 0..w; independence of
// product-state bits gives <Z_w> = prod of per-qubit <Z> over q<=w.
//
// Traffic: 640 KB in + 640 KB out => ~0.2 us at HBM speed. Measured dur_us
// is dominated by harness d_ws re-poison (256 MB fill @ ~40 us) + graph
// launch overhead; kernel itself is launch-latency-bound.

#define N_WIRES 10

__global__ __launch_bounds__(256) void qcircuit_expval(
    const float* __restrict__ x, const float* __restrict__ p,
    float* __restrict__ out, int batch)
{
    __shared__ float cp[N_WIRES];
    if (threadIdx.x < N_WIRES) cp[threadIdx.x] = __cosf(p[threadIdx.x]);
    __syncthreads();

    int b = blockIdx.x * blockDim.x + threadIdx.x;
    if (b >= batch) return;

    // Row of 10 floats = 40 bytes, 8-byte aligned -> 5x float2 vector loads.
    const float2* xr = reinterpret_cast<const float2*>(x + (size_t)b * N_WIRES);
    float2 xv[N_WIRES / 2];
#pragma unroll
    for (int i = 0; i < N_WIRES / 2; ++i) xv[i] = xr[i];

    float r = 1.0f;
    float2 o[N_WIRES / 2];
#pragma unroll
    for (int i = 0; i < N_WIRES / 2; ++i) {
        r *= cp[2 * i]     * __cosf(xv[i].x);
        o[i].x = r;
        r *= cp[2 * i + 1] * __cosf(xv[i].y);
        o[i].y = r;
    }

    float2* orow = reinterpret_cast<float2*>(out + (size_t)b * N_WIRES);
#pragma unroll
    for (int i = 0; i < N_WIRES / 2; ++i) orow[i] = o[i];
}

extern "C" void kernel_launch(void* const* d_in, const int* in_sizes, int n_in,
                              void* d_out, int out_size, void* d_ws, size_t ws_size,
                              hipStream_t stream) {
    const float* x = (const float*)d_in[0];   // (B, 10) float32
    const float* p = (const float*)d_in[1];   // (10,)  float32
    float* out = (float*)d_out;               // (B, 10) float32

    int batch = in_sizes[0] / N_WIRES;
    const int block = 256;
    int grid = (batch + block - 1) / block;   // 64 workgroups for B=16384
    qcircuit_expval<<<grid, block, 0, stream>>>(x, p, out, batch);
}